// Round 10
// baseline (210.420 us; speedup 1.0000x reference)
//
#include <hip/hip_runtime.h>
#include <hip/hip_bf16.h>
#include <math.h>

typedef unsigned int u32;
typedef unsigned short ushort;

constexpr int N_NODES = 10000;
constexpr int N_EDGES = 320000;
constexpr float NEG_SLOPE = 0.2f;

typedef __attribute__((ext_vector_type(8))) short short8;    // 8 x bf16 bits
typedef __attribute__((ext_vector_type(4))) float f32x4;
typedef __attribute__((ext_vector_type(16))) float f32x16;

// ---------------------------------------------------------------------------
// helpers
// ---------------------------------------------------------------------------
__device__ __forceinline__ float lrelu(float x) { return x > 0.f ? x : NEG_SLOPE * x; }
__device__ __forceinline__ float elu(float x)   { return x > 0.f ? x : (expf(x) - 1.f); }

__device__ __forceinline__ ushort f2bf(float x) {
    u32 b = __float_as_uint(x);
    b += 0x7FFFu + ((b >> 16) & 1u);
    return (ushort)(b >> 16);
}
__device__ __forceinline__ float bf2f(ushort u) {
    return __uint_as_float(((u32)u) << 16);
}

__device__ __forceinline__ void gload16(const void* g, void* l) {
    __builtin_amdgcn_global_load_lds(
        (__attribute__((address_space(1))) void*)g,
        (__attribute__((address_space(3))) void*)l, 16, 0, 0);
}

// ---------------------------------------------------------------------------
// K1: fused [hist(+rank)] + [split h -> bf16 hi/lo]
// counts pre-zeroed by hipMemsetAsync. hist blocks first (atomic-bound,
// overlaps the bandwidth-bound split).
// ---------------------------------------------------------------------------
constexpr int NB_HIST  = (N_EDGES + 255) / 256;          // 1250
constexpr int NB_SPLIT = (N_NODES * 512 / 4) / 256;      // 5000

__global__ void prep1_kernel(const float4* __restrict__ h4,
                             ushort* __restrict__ hhi, ushort* __restrict__ hlo,
                             const int* __restrict__ dst, int* __restrict__ counts,
                             int* __restrict__ rank) {
    const int b = blockIdx.x;
    if (b < NB_HIST) {
        const int i = b * 256 + threadIdx.x;
        if (i < N_EDGES) rank[i] = atomicAdd(&counts[dst[i]], 1);
    } else {
        const int i = (b - NB_HIST) * 256 + threadIdx.x;
        const float4 v = h4[i];
        ushort h0 = f2bf(v.x), h1 = f2bf(v.y), h2 = f2bf(v.z), h3 = f2bf(v.w);
        *(ushort4*)&hhi[i * 4] = make_ushort4(h0, h1, h2, h3);
        *(ushort4*)&hlo[i * 4] = make_ushort4(
            f2bf(v.x - bf2f(h0)), f2bf(v.y - bf2f(h1)),
            f2bf(v.z - bf2f(h2)), f2bf(v.w - bf2f(h3)));
    }
}

// ---------------------------------------------------------------------------
// K2: fused [transpose+split W1 (hi/lo)] + [transpose W2 (hi only)]
//     + [wl2/wr2] + [scan block] (hist completed in K1 -> counts final)
// ---------------------------------------------------------------------------
constexpr int NB_T1   = 64;     // W1: 8x8 tiles of 64x64
constexpr int NB_T2   = 8;      // W2: 8x1 tiles
constexpr int NB_WLR2 = 2;      // 512 threads
// block NB_T1+NB_T2+NB_WLR2 (last) = scan

__global__ void prep2_kernel(const float* __restrict__ W1,
                             ushort* __restrict__ w1thi, ushort* __restrict__ w1tlo,
                             const float* __restrict__ W2,
                             ushort* __restrict__ w2thi,
                             const float* __restrict__ al2, const float* __restrict__ ar2,
                             float* __restrict__ wl2, float* __restrict__ wr2,
                             const int* __restrict__ counts, int* __restrict__ offs) {
    __shared__ float smem[64][65];
    const int b = blockIdx.x;
    if (b < NB_T1 + NB_T2) {
        const bool isW1 = b < NB_T1;
        const float* W = isW1 ? W1 : W2;
        const int N  = isW1 ? 512 : 64;
        const int t  = isW1 ? b : (b - NB_T1);
        const int ti = isW1 ? (t & 7) : t;    // K-tile
        const int tj = isW1 ? (t >> 3) : 0;   // N-tile
        const int c  = threadIdx.x & 63;
        const int r0 = threadIdx.x >> 6;      // 0..3
#pragma unroll
        for (int p = 0; p < 16; p++) {
            const int r = p * 4 + r0;
            smem[r][c] = W[(size_t)(ti * 64 + r) * N + tj * 64 + c];
        }
        __syncthreads();
        if (isW1) {
#pragma unroll
            for (int p = 0; p < 16; p++) {
                const int rr = p * 4 + r0;
                const float v = smem[c][rr];
                const ushort hh = f2bf(v);
                w1thi[(size_t)(tj * 64 + rr) * 512 + ti * 64 + c] = hh;
                w1tlo[(size_t)(tj * 64 + rr) * 512 + ti * 64 + c] = f2bf(v - bf2f(hh));
            }
        } else {
#pragma unroll
            for (int p = 0; p < 16; p++) {
                const int rr = p * 4 + r0;
                w2thi[(size_t)(tj * 64 + rr) * 512 + ti * 64 + c] = f2bf(smem[c][rr]);
            }
        }
    } else if (b < NB_T1 + NB_T2 + NB_WLR2) {
        const int k = (b - NB_T1 - NB_T2) * 256 + threadIdx.x;  // [0,512)
        float sl = 0.f, sr = 0.f;
#pragma unroll 8
        for (int d = 0; d < 64; d++) {
            const float w = W2[(size_t)k * 64 + d];
            sl += w * al2[d];
            sr += w * ar2[d];
        }
        wl2[k] = sl;
        wr2[k] = sr;
    } else {
        // scan block: 256 threads, 40 elems/thread
        __shared__ int wsum[4];
        const int tid = threadIdx.x;
        const int lane = tid & 63, wave = tid >> 6;
        const int base = tid * 40;
        int v[40];
        int s = 0;
#pragma unroll
        for (int i = 0; i < 40; i++) {
            v[i] = (base + i < N_NODES) ? counts[base + i] : 0;
            s += v[i];
        }
        int ps = s;
#pragma unroll
        for (int o = 1; o < 64; o <<= 1) {
            const int t = __shfl_up(ps, o);
            if (lane >= o) ps += t;
        }
        if (lane == 63) wsum[wave] = ps;
        __syncthreads();
        if (tid < 4) {
            int t = wsum[tid];
#pragma unroll
            for (int o = 1; o < 4; o <<= 1) {
                const int u = __shfl_up(t, o);
                if (tid >= o) t += u;
            }
            wsum[tid] = t;
        }
        __syncthreads();
        const int wbase = (wave > 0) ? wsum[wave - 1] : 0;
        int run = wbase + ps - s;
#pragma unroll
        for (int i = 0; i < 40; i++) {
            if (base + i < N_NODES) offs[base + i + 1] = run + v[i];
            run += v[i];
        }
        if (tid == 0) offs[0] = 0;
    }
}

// ---------------------------------------------------------------------------
// K3: fused [GEMM1 32x32x16 bf16x3 + el/er epilogue] + [scatter].
// ---------------------------------------------------------------------------
constexpr int NB_GEMM1 = ((N_NODES + 63) / 64) * 4;      // 628
constexpr int NB_SCAT  = (N_EDGES + 255) / 256;          // 1250

__global__ __launch_bounds__(256) void gemm1_scatter_kernel(
    const ushort* __restrict__ Ahi, const ushort* __restrict__ Alo,
    const ushort* __restrict__ Bhi, const ushort* __restrict__ Blo,
    ushort* __restrict__ Cout, int M,
    const float* __restrict__ attn_l, const float* __restrict__ attn_r,
    float* __restrict__ elp, float* __restrict__ erp,
    const int* __restrict__ src, const int* __restrict__ dst,
    const int* __restrict__ rank, const int* __restrict__ offs,
    int* __restrict__ srcs) {
    constexpr int BM = 64, BN = 128, BK = 32, K = 512, N = 512;

    if ((int)blockIdx.x >= NB_GEMM1) {
        const int i = ((int)blockIdx.x - NB_GEMM1) * 256 + threadIdx.x;
        if (i < N_EDGES) srcs[offs[dst[i]] + rank[i]] = src[i];
        return;
    }

    __shared__ __align__(16) ushort sAhi[BM * BK];
    __shared__ __align__(16) ushort sAlo[BM * BK];
    __shared__ __align__(16) ushort sBhi[BN * BK];
    __shared__ __align__(16) ushort sBlo[BN * BK];

    const int tid = threadIdx.x;
    const int wave = tid >> 6, lane = tid & 63;
    const int m0 = ((int)blockIdx.x >> 2) * BM, n0 = ((int)blockIdx.x & 3) * BN;
    const int wm = wave >> 1, wn = wave & 1;
    const int l31 = lane & 31, lh = lane >> 5;

    const int fb = wave * 1024 + lane * 16;

    int arow = m0 + (fb >> 6);
    if (arow > M - 1) arow = M - 1;
    const size_t abyte = (size_t)arow * (K * 2) + (fb & 63);
    size_t bbyte[2];
#pragma unroll
    for (int r = 0; r < 2; r++) {
        const int f = fb + r * 4096;
        bbyte[r] = (size_t)(n0 + (f >> 6)) * (K * 2) + (f & 63);
    }

    f32x16 acc[2] = {};

    for (int k0 = 0; k0 < K; k0 += BK) {
        __syncthreads();
        const size_t kb = (size_t)k0 * 2;
        gload16((const char*)Ahi + abyte + kb, (char*)sAhi + fb);
        gload16((const char*)Alo + abyte + kb, (char*)sAlo + fb);
#pragma unroll
        for (int r = 0; r < 2; r++) {
            const int f = fb + r * 4096;
            gload16((const char*)Bhi + bbyte[r] + kb, (char*)sBhi + f);
            gload16((const char*)Blo + bbyte[r] + kb, (char*)sBlo + f);
        }
        __syncthreads();

#pragma unroll
        for (int ks = 0; ks < 2; ks++) {
            const int koff = ks * 16 + lh * 8;
            const int arw = wm * 32 + l31;
            const short8 ah = *(const short8*)&sAhi[arw * BK + koff];
            const short8 al = *(const short8*)&sAlo[arw * BK + koff];
            short8 bh[2], bl[2];
#pragma unroll
            for (int ni = 0; ni < 2; ni++) {
                const int brw = wn * 64 + ni * 32 + l31;
                bh[ni] = *(const short8*)&sBhi[brw * BK + koff];
                bl[ni] = *(const short8*)&sBlo[brw * BK + koff];
            }
#pragma unroll
            for (int ni = 0; ni < 2; ni++) {
                acc[ni] = __builtin_amdgcn_mfma_f32_32x32x16_bf16(ah, bh[ni], acc[ni], 0, 0, 0);
                acc[ni] = __builtin_amdgcn_mfma_f32_32x32x16_bf16(ah, bl[ni], acc[ni], 0, 0, 0);
                acc[ni] = __builtin_amdgcn_mfma_f32_32x32x16_bf16(al, bh[ni], acc[ni], 0, 0, 0);
            }
        }
    }

    // C layout (m74/m101): col=lane&31, row=(reg&3)+8*(reg>>2)+4*(lane>>5)
#pragma unroll
    for (int reg = 0; reg < 16; reg++) {
        const int grow = m0 + wm * 32 + (reg & 3) + 8 * (reg >> 2) + 4 * lh;
        if (grow < M) {
#pragma unroll
            for (int ni = 0; ni < 2; ni++) {
                const int gcol = n0 + wn * 64 + ni * 32 + l31;
                Cout[(size_t)grow * N + gcol] = f2bf(acc[ni][reg]);
            }
        }
    }

    const int head = (n0 + wn * 64) >> 6;
    float alv[2], arv[2];
#pragma unroll
    for (int ni = 0; ni < 2; ni++) {
        alv[ni] = attn_l[head * 64 + ni * 32 + l31];
        arv[ni] = attn_r[head * 64 + ni * 32 + l31];
    }
#pragma unroll
    for (int reg = 0; reg < 16; reg++) {
        float pl = acc[0][reg] * alv[0] + acc[1][reg] * alv[1];
        float pr = acc[0][reg] * arv[0] + acc[1][reg] * arv[1];
#pragma unroll
        for (int o = 1; o < 32; o <<= 1) {
            pl += __shfl_xor(pl, o);
            pr += __shfl_xor(pr, o);
        }
        const int grow = m0 + wm * 32 + (reg & 3) + 8 * (reg >> 2) + 4 * lh;
        if (l31 == 0 && grow < M) {
            elp[grow * 8 + head] = pl;
            erp[grow * 8 + head] = pr;
        }
    }
}

// ---------------------------------------------------------------------------
// GEMM2 (layer 2): pure bf16, 16x16x32, BM=64 BN=64, bf16 out.
// ---------------------------------------------------------------------------
__global__ __launch_bounds__(256) void gemm2_kernel(
    const ushort* __restrict__ Ahi, const ushort* __restrict__ Bhi,
    ushort* __restrict__ Cout, int M) {
    constexpr int BM = 64, BN = 64, BK = 32, K = 512, N = 64;
    constexpr int WM = 32, WN = 32, MT_M = 2, MT_N = 2;

    __shared__ __align__(16) ushort sA[BM * BK];
    __shared__ __align__(16) ushort sB[BN * BK];

    const int tid = threadIdx.x;
    const int wave = tid >> 6, lane = tid & 63;
    const int m0 = blockIdx.x * BM;
    const int wm = wave >> 1, wn = wave & 1;
    const int quad = lane >> 4, l15 = lane & 15;

    const int fb = wave * 1024 + lane * 16;

    int arow = m0 + (fb >> 6);
    if (arow > M - 1) arow = M - 1;
    const size_t abyte = (size_t)arow * (K * 2) + (fb & 63);
    const size_t bbyte = (size_t)(fb >> 6) * (K * 2) + (fb & 63);

    f32x4 acc[MT_M][MT_N] = {};

    for (int k0 = 0; k0 < K; k0 += BK) {
        __syncthreads();
        const size_t kb = (size_t)k0 * 2;
        gload16((const char*)Ahi + abyte + kb, (char*)sA + fb);
        gload16((const char*)Bhi + bbyte + kb, (char*)sB + fb);
        __syncthreads();

        short8 ah[MT_M], bh[MT_N];
#pragma unroll
        for (int mi = 0; mi < MT_M; mi++) {
            const int row = wm * WM + mi * 16 + l15;
            ah[mi] = *(const short8*)&sA[row * BK + quad * 8];
        }
#pragma unroll
        for (int ni = 0; ni < MT_N; ni++) {
            const int row = wn * WN + ni * 16 + l15;
            bh[ni] = *(const short8*)&sB[row * BK + quad * 8];
        }
#pragma unroll
        for (int mi = 0; mi < MT_M; mi++)
#pragma unroll
            for (int ni = 0; ni < MT_N; ni++)
                acc[mi][ni] = __builtin_amdgcn_mfma_f32_16x16x32_bf16(ah[mi], bh[ni], acc[mi][ni], 0, 0, 0);
    }

#pragma unroll
    for (int mi = 0; mi < MT_M; mi++) {
#pragma unroll
        for (int r = 0; r < 4; r++) {
            const int grow = m0 + wm * WM + mi * 16 + quad * 4 + r;
            if (grow < M) {
#pragma unroll
                for (int ni = 0; ni < MT_N; ni++) {
                    const int gcol = wn * WN + ni * 16 + l15;
                    Cout[(size_t)grow * N + gcol] = f2bf(acc[mi][ni][r]);
                }
            }
        }
    }
}

// ---------------------------------------------------------------------------
// Layer-1 aggregation: one wave per node, 8-deep pipeline. Fused layer-2
// logits (fp32) + bf16 x1 write (hi only).
// ---------------------------------------------------------------------------
__global__ __launch_bounds__(256) void agg1_kernel(
    const ushort* __restrict__ feat, const float* __restrict__ el,
    const float* __restrict__ er, const int* __restrict__ offs,
    const int* __restrict__ srcs, ushort* __restrict__ xhi,
    const float* __restrict__ wl2, const float* __restrict__ wr2,
    float* __restrict__ el2, float* __restrict__ er2) {
    const int tid = threadIdx.x;
    const int wave = tid >> 6, lane = tid & 63;
    const int node = blockIdx.x * 4 + wave;
    const int start = offs[node];
    const int deg = offs[node + 1] - start;
    const int d0 = lane * 8;
    const int myh = lane >> 3;

    if (deg == 0) {
        const ushort4 z = make_ushort4(0, 0, 0, 0);
        *(ushort4*)&xhi[(size_t)node * 512 + d0] = z;
        *(ushort4*)&xhi[(size_t)node * 512 + d0 + 4] = z;
        if (lane == 0) { el2[node] = 0.f; er2[node] = 0.f; }
        return;
    }

    const float4 ea = *(const float4*)&er[node * 8];
    const float4 eb = *(const float4*)&er[node * 8 + 4];
    const float er_my = (myh & 4) ? ((myh & 2) ? ((myh & 1) ? eb.w : eb.z)
                                              : ((myh & 1) ? eb.y : eb.x))
                                  : ((myh & 2) ? ((myh & 1) ? ea.w : ea.z)
                                              : ((myh & 1) ? ea.y : ea.x));

    float acc[8];
#pragma unroll
    for (int i = 0; i < 8; i++) acc[i] = 0.f;
    float ws = 0.f;

    for (int base = 0; base < deg; base += 64) {
        const int has = min(64, deg - base);
        const int s = srcs[start + base + min(lane, has - 1)];
        int j = 0;
        for (; j + 8 <= has; j += 8) {
            int sq[8];
#pragma unroll
            for (int q = 0; q < 8; q++) sq[q] = __shfl(s, j + q);
            float eq[8];
#pragma unroll
            for (int q = 0; q < 8; q++) eq[q] = el[sq[q] * 8 + myh];
            short8 uq[8];
#pragma unroll
            for (int q = 0; q < 8; q++)
                uq[q] = *(const short8*)&feat[(size_t)sq[q] * 512 + d0];
            float wq[8];
#pragma unroll
            for (int q = 0; q < 8; q++) wq[q] = __expf(lrelu(eq[q] + er_my));
#pragma unroll
            for (int q = 0; q < 8; q++) {
#pragma unroll
                for (int i = 0; i < 8; i++)
                    acc[i] += wq[q] * bf2f((ushort)uq[q][i]);
                ws += wq[q];
            }
        }
        for (; j < has; j++) {
            const int sj = __shfl(s, j);
            const float w = __expf(lrelu(el[sj * 8 + myh] + er_my));
            const short8 u = *(const short8*)&feat[(size_t)sj * 512 + d0];
#pragma unroll
            for (int i = 0; i < 8; i++)
                acc[i] += w * bf2f((ushort)u[i]);
            ws += w;
        }
    }

    const float inv = 1.f / ws;
    float o[8];
#pragma unroll
    for (int i = 0; i < 8; i++) o[i] = elu(acc[i] * inv);

    const float4 wla = *(const float4*)&wl2[d0];
    const float4 wlb = *(const float4*)&wl2[d0 + 4];
    const float4 wra = *(const float4*)&wr2[d0];
    const float4 wrb = *(const float4*)&wr2[d0 + 4];
    float pl = o[0] * wla.x + o[1] * wla.y + o[2] * wla.z + o[3] * wla.w
             + o[4] * wlb.x + o[5] * wlb.y + o[6] * wlb.z + o[7] * wlb.w;
    float pr = o[0] * wra.x + o[1] * wra.y + o[2] * wra.z + o[3] * wra.w
             + o[4] * wrb.x + o[5] * wrb.y + o[6] * wrb.z + o[7] * wrb.w;
#pragma unroll
    for (int off = 32; off > 0; off >>= 1) {
        pl += __shfl_xor(pl, off);
        pr += __shfl_xor(pr, off);
    }
    if (lane == 0) { el2[node] = pl; er2[node] = pr; }

    ushort hi[8];
#pragma unroll
    for (int i = 0; i < 8; i++) hi[i] = f2bf(o[i]);
    *(ushort4*)&xhi[(size_t)node * 512 + d0]     = make_ushort4(hi[0], hi[1], hi[2], hi[3]);
    *(ushort4*)&xhi[(size_t)node * 512 + d0 + 4] = make_ushort4(hi[4], hi[5], hi[6], hi[7]);
}

// ---------------------------------------------------------------------------
// Layer-2 aggregation: one wave per node, 8-deep pipeline; bf16 feat2 gather.
// ---------------------------------------------------------------------------
__global__ __launch_bounds__(256) void agg2_kernel(
    const ushort* __restrict__ feat, const float* __restrict__ el,
    const float* __restrict__ er, const int* __restrict__ offs,
    const int* __restrict__ srcs, float* __restrict__ out) {
    const int tid = threadIdx.x;
    const int wave = tid >> 6, lane = tid & 63;
    const int node = blockIdx.x * 4 + wave;
    const int start = offs[node];
    const int deg = offs[node + 1] - start;
    if (deg == 0) { out[(size_t)node * 64 + lane] = 0.f; return; }
    const float ern = er[node];

    float acc = 0.f, ws = 0.f;
    for (int base = 0; base < deg; base += 64) {
        const int has = min(64, deg - base);
        const int s = srcs[start + base + min(lane, has - 1)];
        const float w = __expf(lrelu(el[s] + ern));
        int j = 0;
        for (; j + 8 <= has; j += 8) {
            float aq[8]; int sq[8];
#pragma unroll
            for (int q = 0; q < 8; q++) { aq[q] = __shfl(w, j + q); sq[q] = __shfl(s, j + q); }
            ushort fq[8];
#pragma unroll
            for (int q = 0; q < 8; q++) fq[q] = feat[(size_t)sq[q] * 64 + lane];
#pragma unroll
            for (int q = 0; q < 8; q++) { acc += aq[q] * bf2f(fq[q]); ws += aq[q]; }
        }
        for (; j < has; j++) {
            const float a = __shfl(w, j);
            const int sj = __shfl(s, j);
            acc += a * bf2f(feat[(size_t)sj * 64 + lane]);
            ws += a;
        }
    }
    out[(size_t)node * 64 + lane] = acc / ws;
}

// ---------------------------------------------------------------------------
extern "C" void kernel_launch(void* const* d_in, const int* in_sizes, int n_in,
                              void* d_out, int out_size, void* d_ws, size_t ws_size,
                              hipStream_t stream) {
    const float* h   = (const float*)d_in[0];
    const int*   src = (const int*)d_in[1];
    const int*   dst = (const int*)d_in[2];
    const float* W1  = (const float*)d_in[3];
    const float* al1 = (const float*)d_in[4];
    const float* ar1 = (const float*)d_in[5];
    const float* W2  = (const float*)d_in[6];
    const float* al2 = (const float*)d_in[7];
    const float* ar2 = (const float*)d_in[8];
    float* out = (float*)d_out;

    // workspace carve (16B-aligned chunks)
    char* p = (char*)d_ws;
    ushort* feat1bf = (ushort*)p; p += (size_t)N_NODES * 512 * 2;  // 10.24 MB
    ushort* feat2bf = (ushort*)p; p += (size_t)N_NODES * 64 * 2;   // 1.28 MB
    float* el1   = (float*)p;  p += (size_t)N_NODES * 8 * 4;
    float* er1   = (float*)p;  p += (size_t)N_NODES * 8 * 4;
    float* el2   = (float*)p;  p += (size_t)N_NODES * 4;
    float* er2   = (float*)p;  p += (size_t)N_NODES * 4;
    ushort* xhi  = (ushort*)p; p += (size_t)N_NODES * 512 * 2;     // h_hi -> x1_hi
    ushort* xlo  = (ushort*)p; p += (size_t)N_NODES * 512 * 2;     // h_lo (layer 1 only)
    ushort* w1thi = (ushort*)p; p += (size_t)512 * 512 * 2;
    ushort* w1tlo = (ushort*)p; p += (size_t)512 * 512 * 2;
    ushort* w2thi = (ushort*)p; p += (size_t)64 * 512 * 2;
    float* wl2   = (float*)p;  p += (size_t)512 * 4;
    float* wr2   = (float*)p;  p += (size_t)512 * 4;
    int* counts  = (int*)p;    p += (size_t)N_NODES * 4;
    int* offs    = (int*)p;    p += (size_t)10004 * 4;
    int* rank    = (int*)p;    p += (size_t)N_EDGES * 4;
    int* srcs    = (int*)p;    p += (size_t)N_EDGES * 4;

    // 0: zero counts via DMA fill (graph-capture-safe)
    hipMemsetAsync(counts, 0, (size_t)N_NODES * 4, stream);

    // 1: fused hist + h-split
    prep1_kernel<<<NB_HIST + NB_SPLIT, 256, 0, stream>>>(
        (const float4*)h, xhi, xlo, dst, counts, rank);

    // 2: fused W-transpose/split + wl2/wr2 + scan
    prep2_kernel<<<NB_T1 + NB_T2 + NB_WLR2 + 1, 256, 0, stream>>>(
        W1, w1thi, w1tlo, W2, w2thi, al2, ar2, wl2, wr2, counts, offs);

    // 3: fused GEMM1(+el/er) + scatter
    gemm1_scatter_kernel<<<NB_GEMM1 + NB_SCAT, 256, 0, stream>>>(
        xhi, xlo, w1thi, w1tlo, feat1bf, N_NODES, al1, ar1, el1, er1,
        src, dst, rank, offs, srcs);

    // 4: layer-1 aggregation (+ fused layer-2 logits); x1 -> xhi (bf16)
    agg1_kernel<<<N_NODES / 4, 256, 0, stream>>>(
        feat1bf, el1, er1, offs, srcs, xhi, wl2, wr2, el2, er2);

    // 5: layer-2 GEMM (pure bf16, bf16 out)
    gemm2_kernel<<<(N_NODES + 63) / 64, 256, 0, stream>>>(
        xhi, w2thi, feat2bf, N_NODES);

    // 6: layer-2 aggregation -> out
    agg2_kernel<<<N_NODES / 4, 256, 0, stream>>>(feat2bf, el2, er2, offs, srcs, out);
}

// Round 11
// 192.473 us; speedup vs baseline: 1.0932x; 1.0932x over previous
//
#include <hip/hip_runtime.h>
#include <hip/hip_bf16.h>
#include <math.h>

typedef unsigned int u32;
typedef unsigned short ushort;

constexpr int N_NODES = 10000;
constexpr int N_EDGES = 320000;
constexpr float NEG_SLOPE = 0.2f;

typedef __attribute__((ext_vector_type(8))) _Float16 half8;  // 8 x fp16 (4 VGPRs)
typedef __attribute__((ext_vector_type(4))) float f32x4;
typedef __attribute__((ext_vector_type(16))) float f32x16;

// ---------------------------------------------------------------------------
// helpers
// ---------------------------------------------------------------------------
__device__ __forceinline__ float lrelu(float x) { return x > 0.f ? x : NEG_SLOPE * x; }
__device__ __forceinline__ float elu(float x)   { return x > 0.f ? x : (expf(x) - 1.f); }

__device__ __forceinline__ ushort f2h(float x) {
    _Float16 h = (_Float16)x;                 // RNE
    return __builtin_bit_cast(ushort, h);
}
__device__ __forceinline__ float h2f(ushort u) {
    return (float)__builtin_bit_cast(_Float16, u);
}

__device__ __forceinline__ void gload16(const void* g, void* l) {
    __builtin_amdgcn_global_load_lds(
        (__attribute__((address_space(1))) void*)g,
        (__attribute__((address_space(3))) void*)l, 16, 0, 0);
}

// ---------------------------------------------------------------------------
// K1: fused [hist(+rank)] + [h -> fp16]
// counts pre-zeroed by hipMemsetAsync. hist blocks first (atomic-bound,
// overlaps the bandwidth-bound convert).
// ---------------------------------------------------------------------------
constexpr int NB_HIST  = (N_EDGES + 255) / 256;          // 1250
constexpr int NB_SPLIT = (N_NODES * 512 / 4) / 256;      // 5000

__global__ void prep1_kernel(const float4* __restrict__ h4,
                             ushort* __restrict__ xh,
                             const int* __restrict__ dst, int* __restrict__ counts,
                             int* __restrict__ rank) {
    const int b = blockIdx.x;
    if (b < NB_HIST) {
        const int i = b * 256 + threadIdx.x;
        if (i < N_EDGES) rank[i] = atomicAdd(&counts[dst[i]], 1);
    } else {
        const int i = (b - NB_HIST) * 256 + threadIdx.x;
        const float4 v = h4[i];
        *(ushort4*)&xh[i * 4] = make_ushort4(f2h(v.x), f2h(v.y), f2h(v.z), f2h(v.w));
    }
}

// ---------------------------------------------------------------------------
// K2: fused [transpose W1 -> fp16] + [transpose W2 -> fp16] + [wl2/wr2]
//     + [scan block] (counts final after K1)
// ---------------------------------------------------------------------------
constexpr int NB_T1   = 64;     // W1: 8x8 tiles of 64x64
constexpr int NB_T2   = 8;      // W2: 8x1 tiles
constexpr int NB_WLR2 = 2;      // 512 threads

__global__ void prep2_kernel(const float* __restrict__ W1,
                             ushort* __restrict__ w1t,
                             const float* __restrict__ W2,
                             ushort* __restrict__ w2t,
                             const float* __restrict__ al2, const float* __restrict__ ar2,
                             float* __restrict__ wl2, float* __restrict__ wr2,
                             const int* __restrict__ counts, int* __restrict__ offs) {
    __shared__ float smem[64][65];
    const int b = blockIdx.x;
    if (b < NB_T1 + NB_T2) {
        const bool isW1 = b < NB_T1;
        const float* W = isW1 ? W1 : W2;
        ushort* wt = isW1 ? w1t : w2t;
        const int N  = isW1 ? 512 : 64;
        const int t  = isW1 ? b : (b - NB_T1);
        const int ti = isW1 ? (t & 7) : t;    // K-tile
        const int tj = isW1 ? (t >> 3) : 0;   // N-tile
        const int c  = threadIdx.x & 63;
        const int r0 = threadIdx.x >> 6;      // 0..3
#pragma unroll
        for (int p = 0; p < 16; p++) {
            const int r = p * 4 + r0;
            smem[r][c] = W[(size_t)(ti * 64 + r) * N + tj * 64 + c];
        }
        __syncthreads();
#pragma unroll
        for (int p = 0; p < 16; p++) {
            const int rr = p * 4 + r0;
            wt[(size_t)(tj * 64 + rr) * 512 + ti * 64 + c] = f2h(smem[c][rr]);
        }
    } else if (b < NB_T1 + NB_T2 + NB_WLR2) {
        const int k = (b - NB_T1 - NB_T2) * 256 + threadIdx.x;  // [0,512)
        float sl = 0.f, sr = 0.f;
#pragma unroll 8
        for (int d = 0; d < 64; d++) {
            const float w = W2[(size_t)k * 64 + d];
            sl += w * al2[d];
            sr += w * ar2[d];
        }
        wl2[k] = sl;
        wr2[k] = sr;
    } else {
        // scan block: 256 threads, 40 elems/thread
        __shared__ int wsum[4];
        const int tid = threadIdx.x;
        const int lane = tid & 63, wave = tid >> 6;
        const int base = tid * 40;
        int v[40];
        int s = 0;
#pragma unroll
        for (int i = 0; i < 40; i++) {
            v[i] = (base + i < N_NODES) ? counts[base + i] : 0;
            s += v[i];
        }
        int ps = s;
#pragma unroll
        for (int o = 1; o < 64; o <<= 1) {
            const int t = __shfl_up(ps, o);
            if (lane >= o) ps += t;
        }
        if (lane == 63) wsum[wave] = ps;
        __syncthreads();
        if (tid < 4) {
            int t = wsum[tid];
#pragma unroll
            for (int o = 1; o < 4; o <<= 1) {
                const int u = __shfl_up(t, o);
                if (tid >= o) t += u;
            }
            wsum[tid] = t;
        }
        __syncthreads();
        const int wbase = (wave > 0) ? wsum[wave - 1] : 0;
        int run = wbase + ps - s;
#pragma unroll
        for (int i = 0; i < 40; i++) {
            if (base + i < N_NODES) offs[base + i + 1] = run + v[i];
            run += v[i];
        }
        if (tid == 0) offs[0] = 0;
    }
}

// ---------------------------------------------------------------------------
// K3: fused [GEMM1 32x32x16 PURE fp16 + el/er epilogue] + [scatter].
// Single MFMA pass (fp16 11-bit mantissa: dot-err sigma ~5e-4, under the
// downstream quantization floor). BM=64 BN=128 BK=32.
// ---------------------------------------------------------------------------
constexpr int NB_GEMM1 = ((N_NODES + 63) / 64) * 4;      // 628
constexpr int NB_SCAT  = (N_EDGES + 255) / 256;          // 1250

__global__ __launch_bounds__(256) void gemm1_scatter_kernel(
    const ushort* __restrict__ A, const ushort* __restrict__ B,
    ushort* __restrict__ Cout, int M,
    const float* __restrict__ attn_l, const float* __restrict__ attn_r,
    float* __restrict__ elp, float* __restrict__ erp,
    const int* __restrict__ src, const int* __restrict__ dst,
    const int* __restrict__ rank, const int* __restrict__ offs,
    int* __restrict__ srcs) {
    constexpr int BM = 64, BN = 128, BK = 32, K = 512, N = 512;

    if ((int)blockIdx.x >= NB_GEMM1) {
        const int i = ((int)blockIdx.x - NB_GEMM1) * 256 + threadIdx.x;
        if (i < N_EDGES) srcs[offs[dst[i]] + rank[i]] = src[i];
        return;
    }

    __shared__ __align__(16) ushort sA[BM * BK];   // 4 KB
    __shared__ __align__(16) ushort sB[BN * BK];   // 8 KB

    const int tid = threadIdx.x;
    const int wave = tid >> 6, lane = tid & 63;
    const int m0 = ((int)blockIdx.x >> 2) * BM, n0 = ((int)blockIdx.x & 3) * BN;
    const int wm = wave >> 1, wn = wave & 1;
    const int l31 = lane & 31, lh = lane >> 5;

    const int fb = wave * 1024 + lane * 16;   // [0,4096)

    int arow = m0 + (fb >> 6);
    if (arow > M - 1) arow = M - 1;
    const size_t abyte = (size_t)arow * (K * 2) + (fb & 63);
    size_t bbyte[2];
#pragma unroll
    for (int r = 0; r < 2; r++) {
        const int f = fb + r * 4096;
        bbyte[r] = (size_t)(n0 + (f >> 6)) * (K * 2) + (f & 63);
    }

    f32x16 acc[2] = {};

    for (int k0 = 0; k0 < K; k0 += BK) {
        __syncthreads();
        const size_t kb = (size_t)k0 * 2;
        gload16((const char*)A + abyte + kb, (char*)sA + fb);
#pragma unroll
        for (int r = 0; r < 2; r++) {
            const int f = fb + r * 4096;
            gload16((const char*)B + bbyte[r] + kb, (char*)sB + f);
        }
        __syncthreads();

#pragma unroll
        for (int ks = 0; ks < 2; ks++) {
            const int koff = ks * 16 + lh * 8;
            const half8 ah = *(const half8*)&sA[(wm * 32 + l31) * BK + koff];
#pragma unroll
            for (int ni = 0; ni < 2; ni++) {
                const half8 bh = *(const half8*)&sB[(wn * 64 + ni * 32 + l31) * BK + koff];
                acc[ni] = __builtin_amdgcn_mfma_f32_32x32x16_f16(ah, bh, acc[ni], 0, 0, 0);
            }
        }
    }

    // C layout (m74/m101, dtype-independent): col=lane&31,
    // row=(reg&3)+8*(reg>>2)+4*(lane>>5)
#pragma unroll
    for (int reg = 0; reg < 16; reg++) {
        const int grow = m0 + wm * 32 + (reg & 3) + 8 * (reg >> 2) + 4 * lh;
        if (grow < M) {
#pragma unroll
            for (int ni = 0; ni < 2; ni++) {
                const int gcol = n0 + wn * 64 + ni * 32 + l31;
                Cout[(size_t)grow * N + gcol] = f2h(acc[ni][reg]);
            }
        }
    }

    const int head = (n0 + wn * 64) >> 6;
    float alv[2], arv[2];
#pragma unroll
    for (int ni = 0; ni < 2; ni++) {
        alv[ni] = attn_l[head * 64 + ni * 32 + l31];
        arv[ni] = attn_r[head * 64 + ni * 32 + l31];
    }
#pragma unroll
    for (int reg = 0; reg < 16; reg++) {
        float pl = acc[0][reg] * alv[0] + acc[1][reg] * alv[1];
        float pr = acc[0][reg] * arv[0] + acc[1][reg] * arv[1];
#pragma unroll
        for (int o = 1; o < 32; o <<= 1) {
            pl += __shfl_xor(pl, o);
            pr += __shfl_xor(pr, o);
        }
        const int grow = m0 + wm * 32 + (reg & 3) + 8 * (reg >> 2) + 4 * lh;
        if (l31 == 0 && grow < M) {
            elp[grow * 8 + head] = pl;
            erp[grow * 8 + head] = pr;
        }
    }
}

// ---------------------------------------------------------------------------
// GEMM2 (layer 2): pure fp16, 16x16x32, BM=64 BN=64, fp16 out.
// ---------------------------------------------------------------------------
__global__ __launch_bounds__(256) void gemm2_kernel(
    const ushort* __restrict__ A, const ushort* __restrict__ B,
    ushort* __restrict__ Cout, int M) {
    constexpr int BM = 64, BN = 64, BK = 32, K = 512, N = 64;
    constexpr int WM = 32, WN = 32, MT_M = 2, MT_N = 2;

    __shared__ __align__(16) ushort sA[BM * BK];
    __shared__ __align__(16) ushort sB[BN * BK];

    const int tid = threadIdx.x;
    const int wave = tid >> 6, lane = tid & 63;
    const int m0 = blockIdx.x * BM;
    const int wm = wave >> 1, wn = wave & 1;
    const int quad = lane >> 4, l15 = lane & 15;

    const int fb = wave * 1024 + lane * 16;

    int arow = m0 + (fb >> 6);
    if (arow > M - 1) arow = M - 1;
    const size_t abyte = (size_t)arow * (K * 2) + (fb & 63);
    const size_t bbyte = (size_t)(fb >> 6) * (K * 2) + (fb & 63);

    f32x4 acc[MT_M][MT_N] = {};

    for (int k0 = 0; k0 < K; k0 += BK) {
        __syncthreads();
        const size_t kb = (size_t)k0 * 2;
        gload16((const char*)A + abyte + kb, (char*)sA + fb);
        gload16((const char*)B + bbyte + kb, (char*)sB + fb);
        __syncthreads();

        half8 ah[MT_M], bh[MT_N];
#pragma unroll
        for (int mi = 0; mi < MT_M; mi++) {
            const int row = wm * WM + mi * 16 + l15;
            ah[mi] = *(const half8*)&sA[row * BK + quad * 8];
        }
#pragma unroll
        for (int ni = 0; ni < MT_N; ni++) {
            const int row = wn * WN + ni * 16 + l15;
            bh[ni] = *(const half8*)&sB[row * BK + quad * 8];
        }
#pragma unroll
        for (int mi = 0; mi < MT_M; mi++)
#pragma unroll
            for (int ni = 0; ni < MT_N; ni++)
                acc[mi][ni] = __builtin_amdgcn_mfma_f32_16x16x32_f16(ah[mi], bh[ni], acc[mi][ni], 0, 0, 0);
    }

#pragma unroll
    for (int mi = 0; mi < MT_M; mi++) {
#pragma unroll
        for (int r = 0; r < 4; r++) {
            const int grow = m0 + wm * WM + mi * 16 + quad * 4 + r;
            if (grow < M) {
#pragma unroll
                for (int ni = 0; ni < MT_N; ni++) {
                    const int gcol = wn * WN + ni * 16 + l15;
                    Cout[(size_t)grow * N + gcol] = f2h(acc[mi][ni][r]);
                }
            }
        }
    }
}

// ---------------------------------------------------------------------------
// Layer-1 aggregation: one wave per node, 8-deep pipeline, fp16 feat gather.
// Fused layer-2 logits (fp32) + fp16 x1 write.
// ---------------------------------------------------------------------------
__global__ __launch_bounds__(256) void agg1_kernel(
    const ushort* __restrict__ feat, const float* __restrict__ el,
    const float* __restrict__ er, const int* __restrict__ offs,
    const int* __restrict__ srcs, ushort* __restrict__ xh,
    const float* __restrict__ wl2, const float* __restrict__ wr2,
    float* __restrict__ el2, float* __restrict__ er2) {
    const int tid = threadIdx.x;
    const int wave = tid >> 6, lane = tid & 63;
    const int node = blockIdx.x * 4 + wave;
    const int start = offs[node];
    const int deg = offs[node + 1] - start;
    const int d0 = lane * 8;
    const int myh = lane >> 3;

    if (deg == 0) {
        const ushort4 z = make_ushort4(0, 0, 0, 0);
        *(ushort4*)&xh[(size_t)node * 512 + d0] = z;
        *(ushort4*)&xh[(size_t)node * 512 + d0 + 4] = z;
        if (lane == 0) { el2[node] = 0.f; er2[node] = 0.f; }
        return;
    }

    const float4 ea = *(const float4*)&er[node * 8];
    const float4 eb = *(const float4*)&er[node * 8 + 4];
    const float er_my = (myh & 4) ? ((myh & 2) ? ((myh & 1) ? eb.w : eb.z)
                                              : ((myh & 1) ? eb.y : eb.x))
                                  : ((myh & 2) ? ((myh & 1) ? ea.w : ea.z)
                                              : ((myh & 1) ? ea.y : ea.x));

    float acc[8];
#pragma unroll
    for (int i = 0; i < 8; i++) acc[i] = 0.f;
    float ws = 0.f;

    for (int base = 0; base < deg; base += 64) {
        const int has = min(64, deg - base);
        const int s = srcs[start + base + min(lane, has - 1)];
        int j = 0;
        for (; j + 8 <= has; j += 8) {
            int sq[8];
#pragma unroll
            for (int q = 0; q < 8; q++) sq[q] = __shfl(s, j + q);
            float eq[8];
#pragma unroll
            for (int q = 0; q < 8; q++) eq[q] = el[sq[q] * 8 + myh];
            half8 uq[8];
#pragma unroll
            for (int q = 0; q < 8; q++)
                uq[q] = *(const half8*)&feat[(size_t)sq[q] * 512 + d0];
            float wq[8];
#pragma unroll
            for (int q = 0; q < 8; q++) wq[q] = __expf(lrelu(eq[q] + er_my));
#pragma unroll
            for (int q = 0; q < 8; q++) {
#pragma unroll
                for (int i = 0; i < 8; i++)
                    acc[i] += wq[q] * (float)uq[q][i];
                ws += wq[q];
            }
        }
        for (; j < has; j++) {
            const int sj = __shfl(s, j);
            const float w = __expf(lrelu(el[sj * 8 + myh] + er_my));
            const half8 u = *(const half8*)&feat[(size_t)sj * 512 + d0];
#pragma unroll
            for (int i = 0; i < 8; i++)
                acc[i] += w * (float)u[i];
            ws += w;
        }
    }

    const float inv = 1.f / ws;
    float o[8];
#pragma unroll
    for (int i = 0; i < 8; i++) o[i] = elu(acc[i] * inv);

    const float4 wla = *(const float4*)&wl2[d0];
    const float4 wlb = *(const float4*)&wl2[d0 + 4];
    const float4 wra = *(const float4*)&wr2[d0];
    const float4 wrb = *(const float4*)&wr2[d0 + 4];
    float pl = o[0] * wla.x + o[1] * wla.y + o[2] * wla.z + o[3] * wla.w
             + o[4] * wlb.x + o[5] * wlb.y + o[6] * wlb.z + o[7] * wlb.w;
    float pr = o[0] * wra.x + o[1] * wra.y + o[2] * wra.z + o[3] * wra.w
             + o[4] * wrb.x + o[5] * wrb.y + o[6] * wrb.z + o[7] * wrb.w;
#pragma unroll
    for (int off = 32; off > 0; off >>= 1) {
        pl += __shfl_xor(pl, off);
        pr += __shfl_xor(pr, off);
    }
    if (lane == 0) { el2[node] = pl; er2[node] = pr; }

    ushort hh[8];
#pragma unroll
    for (int i = 0; i < 8; i++) hh[i] = f2h(o[i]);
    *(ushort4*)&xh[(size_t)node * 512 + d0]     = make_ushort4(hh[0], hh[1], hh[2], hh[3]);
    *(ushort4*)&xh[(size_t)node * 512 + d0 + 4] = make_ushort4(hh[4], hh[5], hh[6], hh[7]);
}

// ---------------------------------------------------------------------------
// Layer-2 aggregation: one wave per node, 8-deep pipeline; fp16 feat2 gather.
// ---------------------------------------------------------------------------
__global__ __launch_bounds__(256) void agg2_kernel(
    const ushort* __restrict__ feat, const float* __restrict__ el,
    const float* __restrict__ er, const int* __restrict__ offs,
    const int* __restrict__ srcs, float* __restrict__ out) {
    const int tid = threadIdx.x;
    const int wave = tid >> 6, lane = tid & 63;
    const int node = blockIdx.x * 4 + wave;
    const int start = offs[node];
    const int deg = offs[node + 1] - start;
    if (deg == 0) { out[(size_t)node * 64 + lane] = 0.f; return; }
    const float ern = er[node];

    float acc = 0.f, ws = 0.f;
    for (int base = 0; base < deg; base += 64) {
        const int has = min(64, deg - base);
        const int s = srcs[start + base + min(lane, has - 1)];
        const float w = __expf(lrelu(el[s] + ern));
        int j = 0;
        for (; j + 8 <= has; j += 8) {
            float aq[8]; int sq[8];
#pragma unroll
            for (int q = 0; q < 8; q++) { aq[q] = __shfl(w, j + q); sq[q] = __shfl(s, j + q); }
            ushort fq[8];
#pragma unroll
            for (int q = 0; q < 8; q++) fq[q] = feat[(size_t)sq[q] * 64 + lane];
#pragma unroll
            for (int q = 0; q < 8; q++) { acc += aq[q] * h2f(fq[q]); ws += aq[q]; }
        }
        for (; j < has; j++) {
            const float a = __shfl(w, j);
            const int sj = __shfl(s, j);
            acc += a * h2f(feat[(size_t)sj * 64 + lane]);
            ws += a;
        }
    }
    out[(size_t)node * 64 + lane] = acc / ws;
}

// ---------------------------------------------------------------------------
extern "C" void kernel_launch(void* const* d_in, const int* in_sizes, int n_in,
                              void* d_out, int out_size, void* d_ws, size_t ws_size,
                              hipStream_t stream) {
    const float* h   = (const float*)d_in[0];
    const int*   src = (const int*)d_in[1];
    const int*   dst = (const int*)d_in[2];
    const float* W1  = (const float*)d_in[3];
    const float* al1 = (const float*)d_in[4];
    const float* ar1 = (const float*)d_in[5];
    const float* W2  = (const float*)d_in[6];
    const float* al2 = (const float*)d_in[7];
    const float* ar2 = (const float*)d_in[8];
    float* out = (float*)d_out;

    // workspace carve (16B-aligned chunks)
    char* p = (char*)d_ws;
    ushort* feat1 = (ushort*)p; p += (size_t)N_NODES * 512 * 2;   // fp16, 10.24 MB
    ushort* feat2 = (ushort*)p; p += (size_t)N_NODES * 64 * 2;    // fp16
    float* el1   = (float*)p;  p += (size_t)N_NODES * 8 * 4;
    float* er1   = (float*)p;  p += (size_t)N_NODES * 8 * 4;
    float* el2   = (float*)p;  p += (size_t)N_NODES * 4;
    float* er2   = (float*)p;  p += (size_t)N_NODES * 4;
    ushort* xh   = (ushort*)p; p += (size_t)N_NODES * 512 * 2;    // h fp16 -> x1 fp16
    ushort* w1t  = (ushort*)p; p += (size_t)512 * 512 * 2;        // fp16
    ushort* w2t  = (ushort*)p; p += (size_t)64 * 512 * 2;         // fp16
    float* wl2   = (float*)p;  p += (size_t)512 * 4;
    float* wr2   = (float*)p;  p += (size_t)512 * 4;
    int* counts  = (int*)p;    p += (size_t)N_NODES * 4;
    int* offs    = (int*)p;    p += (size_t)10004 * 4;
    int* rank    = (int*)p;    p += (size_t)N_EDGES * 4;
    int* srcs    = (int*)p;    p += (size_t)N_EDGES * 4;

    // 0: zero counts via DMA fill (graph-capture-safe)
    hipMemsetAsync(counts, 0, (size_t)N_NODES * 4, stream);

    // 1: fused hist + h->fp16
    prep1_kernel<<<NB_HIST + NB_SPLIT, 256, 0, stream>>>(
        (const float4*)h, xh, dst, counts, rank);

    // 2: fused W-transpose (fp16) + wl2/wr2 + scan
    prep2_kernel<<<NB_T1 + NB_T2 + NB_WLR2 + 1, 256, 0, stream>>>(
        W1, w1t, W2, w2t, al2, ar2, wl2, wr2, counts, offs);

    // 3: fused GEMM1 (pure fp16, + el/er) + scatter
    gemm1_scatter_kernel<<<NB_GEMM1 + NB_SCAT, 256, 0, stream>>>(
        xh, w1t, feat1, N_NODES, al1, ar1, el1, er1,
        src, dst, rank, offs, srcs);

    // 4: layer-1 aggregation (+ fused layer-2 logits); x1 -> xh (fp16)
    agg1_kernel<<<N_NODES / 4, 256, 0, stream>>>(
        feat1, el1, er1, offs, srcs, xh, wl2, wr2, el2, er2);

    // 5: layer-2 GEMM (pure fp16)
    gemm2_kernel<<<(N_NODES + 63) / 64, 256, 0, stream>>>(
        xh, w2t, feat2, N_NODES);

    // 6: layer-2 aggregation -> out
    agg2_kernel<<<N_NODES / 4, 256, 0, stream>>>(feat2, el2, er2, offs, srcs, out);
}